// Round 1
// baseline (224.647 us; speedup 1.0000x reference)
//
#include <hip/hip_runtime.h>

#define NDATES 64
#define MASSETS 64
#define NSIMS 32768
#define SB 64   // sims per block

typedef __attribute__((ext_vector_type(8))) short bf16x8;
typedef __attribute__((ext_vector_type(4))) float f32x4;

__device__ __forceinline__ unsigned short f2bf(float f) {
    union { float f; unsigned u; } c; c.f = f;
    unsigned x = c.u;
    x += 0x7FFFu + ((x >> 16) & 1u);   // round-to-nearest-even
    return (unsigned short)(x >> 16);
}

__global__ __launch_bounds__(256) void evo_lognormal_kernel(
    const float* __restrict__ cov,   // [64][64][64]
    const float* __restrict__ var,   // [64][64]
    const float* __restrict__ z,     // [64][64][32768]
    float* __restrict__ out)         // [64][64][32768]
{
    // z tile for one date, sim-major [s][k] bf16, XOR-swizzled: k ^ ((s&7)<<3)
    __shared__ __align__(16) unsigned short zs[SB * 64];

    const int t    = threadIdx.x;     // 0..255
    const int wv   = t >> 6;          // wave 0..3 -> row tile
    const int lane = t & 63;
    const int Q    = lane >> 2;       // 0..15
    const int q    = lane & 3;        // 0..3
    const int l15  = lane & 15;
    const int lg   = lane >> 4;       // 0..3
    const int s0   = blockIdx.x * SB;

    f32x4 acc[4];
    #pragma unroll
    for (int i = 0; i < 4; ++i) acc[i] = f32x4{0.f, 0.f, 0.f, 0.f};
    float vs0 = 0.f, vs1 = 0.f, vs2 = 0.f, vs3 = 0.f;

    const int arow = wv * 16 + l15;         // A-fragment row (cov row)
    const int r0   = wv * 16 + (lg << 2);   // first C/D row of this lane

    for (int d = 0; d < NDATES; ++d) {
        const float* zd = z + ((size_t)d << 21) + s0;

        __syncthreads();   // previous date's LDS reads done before overwrite

        // ---- stage z[d][0..63][s0..s0+63] -> LDS bf16, transposed to [s][k] ----
        #pragma unroll
        for (int it = 0; it < 4; ++it) {
            const int kb = it * 16 + wv * 4;           // quad's k base (wave-uniform)
            const float4 v4 = *reinterpret_cast<const float4*>(
                zd + (size_t)(kb + q) * NSIMS + 4 * Q);
            float v0 = v4.x, v1 = v4.y, v2 = v4.z, v3 = v4.w;
            // 4x4 transpose within the quad (lanes 4Q..4Q+3) via shfl_xor
            float s01 = __shfl_xor(v1, 1), s10 = __shfl_xor(v0, 1);
            float s23 = __shfl_xor(v3, 1), s32 = __shfl_xor(v2, 1);
            float a0 = (q & 1) ? s01 : v0;
            float a1 = (q & 1) ? v1  : s10;
            float a2 = (q & 1) ? s23 : v2;
            float a3 = (q & 1) ? v3  : s32;
            float u02 = __shfl_xor(a2, 2), u20 = __shfl_xor(a0, 2);
            float u13 = __shfl_xor(a3, 2), u31 = __shfl_xor(a1, 2);
            float w0 = (q & 2) ? u02 : a0;
            float w1 = (q & 2) ? u13 : a1;
            float w2 = (q & 2) ? a2  : u20;
            float w3 = (q & 2) ? a3  : u31;
            // now this thread holds z[kb+0..3][s0 + 4Q + q]
            const int sh = 4 * Q + q;
            unsigned lo = (unsigned)f2bf(w0) | ((unsigned)f2bf(w1) << 16);
            unsigned hi = (unsigned)f2bf(w2) | ((unsigned)f2bf(w3) << 16);
            const int u = sh * 64 + (kb ^ ((sh & 7) << 3));
            *reinterpret_cast<uint2*>(&zs[u]) = make_uint2(lo, hi);
        }

        // ---- A fragments straight from global cov (L2-resident, 1 MiB total) ----
        const float* cbase = cov + (((size_t)d * 64 + arow) << 6) + (lg << 3);
        const float4 c0 = *reinterpret_cast<const float4*>(cbase);
        const float4 c1 = *reinterpret_cast<const float4*>(cbase + 4);
        const float4 c2 = *reinterpret_cast<const float4*>(cbase + 32);
        const float4 c3 = *reinterpret_cast<const float4*>(cbase + 36);
        bf16x8 afr0, afr1;
        afr0[0] = (short)f2bf(c0.x); afr0[1] = (short)f2bf(c0.y);
        afr0[2] = (short)f2bf(c0.z); afr0[3] = (short)f2bf(c0.w);
        afr0[4] = (short)f2bf(c1.x); afr0[5] = (short)f2bf(c1.y);
        afr0[6] = (short)f2bf(c1.z); afr0[7] = (short)f2bf(c1.w);
        afr1[0] = (short)f2bf(c2.x); afr1[1] = (short)f2bf(c2.y);
        afr1[2] = (short)f2bf(c2.z); afr1[3] = (short)f2bf(c2.w);
        afr1[4] = (short)f2bf(c3.x); afr1[5] = (short)f2bf(c3.y);
        afr1[6] = (short)f2bf(c3.z); afr1[7] = (short)f2bf(c3.w);

        __syncthreads();   // tile staged

        // ---- MFMA: acc never resets -> cumsum over dates is free ----
        #pragma unroll
        for (int ct = 0; ct < 4; ++ct) {
            const int sl = ct * 16 + l15;
            const int u0 = sl * 64 + ((lg << 3) ^ ((l15 & 7) << 3));
            bf16x8 b0 = *reinterpret_cast<const bf16x8*>(&zs[u0]);
            bf16x8 b1 = *reinterpret_cast<const bf16x8*>(&zs[u0 ^ 32]);
            acc[ct] = __builtin_amdgcn_mfma_f32_16x16x32_bf16(afr0, b0, acc[ct], 0, 0, 0);
            acc[ct] = __builtin_amdgcn_mfma_f32_16x16x32_bf16(afr1, b1, acc[ct], 0, 0, 0);
        }

        // ---- running var/2 cumsum for this lane's 4 rows ----
        const float* vp = var + d * 64 + r0;
        vs0 += 0.5f * vp[0];
        vs1 += 0.5f * vp[1];
        vs2 += 0.5f * vp[2];
        vs3 += 0.5f * vp[3];

        // ---- store this date's logsamples ----
        float* ob = out + (((size_t)d * 64 + r0) << 15) + s0 + l15;
        #pragma unroll
        for (int ct = 0; ct < 4; ++ct) {
            ob[ct * 16]                = acc[ct][0] - vs0;
            ob[(1 << 15) + ct * 16]    = acc[ct][1] - vs1;
            ob[(2 << 15) + ct * 16]    = acc[ct][2] - vs2;
            ob[(3 << 15) + ct * 16]    = acc[ct][3] - vs3;
        }
    }
}

extern "C" void kernel_launch(void* const* d_in, const int* in_sizes, int n_in,
                              void* d_out, int out_size, void* d_ws, size_t ws_size,
                              hipStream_t stream) {
    const float* cov = (const float*)d_in[0];
    const float* var = (const float*)d_in[1];
    const float* z   = (const float*)d_in[2];
    float* out = (float*)d_out;
    dim3 grid(NSIMS / SB);   // 512 blocks
    dim3 block(256);
    evo_lognormal_kernel<<<grid, block, 0, stream>>>(cov, var, z, out);
}